// Round 12
// baseline (376.560 us; speedup 1.0000x reference)
//
#include <hip/hip_runtime.h>
#include <hip/hip_bf16.h>
#include <hip/hip_fp16.h>

#define FDIM 64

// Bucketed CSR build parameters
#define NBLK_G 256        // chunk-grid for p1
#define CHUNK_CAP 8192    // max edges per chunk block (32 KB LDS stage)
#define BKT_SHIFT 7
#define BKT_NODES 128     // dest nodes per bucket
#define NB_MAX 512        // max buckets (N <= 65536)
#define STCAP 8192        // P4 LDS stage cap (edges)

__device__ __forceinline__ int clampi(int v, int n) { return min(max(v, 0), n - 1); }

// --------------------- convert fp32 -> fp16 shadow table (x4) ---------------
__global__ __launch_bounds__(256) void convert_half4(
    const float4* __restrict__ in4, __half2* __restrict__ out2, int n4)
{
    int i = blockIdx.x * 256 + threadIdx.x;
    if (i >= n4) return;
    float4 v = in4[i];
    out2[2 * i]     = __floats2half2_rn(v.x, v.y);
    out2[2 * i + 1] = __floats2half2_rn(v.z, v.w);
}

// ---- P1: block-local bin + contiguous stage + counts + starts table --------
__global__ __launch_bounds__(512) void p1_bin_stage(
    const int* __restrict__ rows, const int* __restrict__ cols,
    unsigned* __restrict__ pairs1, int* __restrict__ blockcnt,
    int* __restrict__ startsTbl, int n, int E, int nb, int chunk)
{
    __shared__ unsigned stage[CHUNK_CAP];
    __shared__ int hist[NB_MAX];
    __shared__ int curs[NB_MAX];
    int tid = threadIdx.x;
    int base = blockIdx.x * chunk;
    int cnt = E - base; if (cnt > chunk) cnt = chunk; if (cnt < 0) cnt = 0;
    for (int i = tid; i < NB_MAX; i += 512) hist[i] = 0;
    __syncthreads();
    for (int i = tid; i < cnt; i += 512)
        atomicAdd(&hist[clampi(cols[base + i], n) >> BKT_SHIFT], 1);
    __syncthreads();
    for (int b = tid; b < nb; b += 512) blockcnt[blockIdx.x * nb + b] = hist[b];
    __syncthreads();
    for (int off = 1; off < NB_MAX; off <<= 1) {
        int t = (tid >= off) ? hist[tid - off] : 0;
        __syncthreads();
        hist[tid] += t;
        __syncthreads();
    }
    curs[tid] = (tid == 0) ? 0 : hist[tid - 1];
    __syncthreads();
    // persist chunk-local exclusive starts BEFORE atomics mutate curs
    for (int b = tid; b < nb; b += 512) startsTbl[blockIdx.x * nb + b] = curs[b];
    __syncthreads();
    for (int i = tid; i < cnt; i += 512) {
        int c = clampi(cols[base + i], n);
        int r = clampi(rows[base + i], n);
        int p = atomicAdd(&curs[c >> BKT_SHIFT], 1);
        stage[p] = ((unsigned)r << 16) | (unsigned)c;
    }
    __syncthreads();
    for (int i = tid; i < cnt; i += 512) pairs1[base + i] = stage[i];
}

// --------------------- P2a: per-bucket column scan (1 wave / bucket) --------
__global__ __launch_bounds__(64) void p2a_colscan(
    int* __restrict__ blockcnt, int* __restrict__ bucketTot, int nb, int nblk)
{
    int b = blockIdx.x;
    int lane = threadIdx.x;
    int chunk = (nblk + 63) >> 6;
    int beg = lane * chunk;
    int endi = min(beg + chunk, nblk);
    int vals[8];
    int s = 0;
    for (int i = beg, j = 0; i < endi; ++i, ++j) {
        vals[j] = blockcnt[(size_t)i * nb + b];
        s += vals[j];
    }
    int incl = s;
#pragma unroll
    for (int o = 1; o < 64; o <<= 1) {
        int t = __shfl_up(incl, o, 64);
        if (lane >= o) incl += t;
    }
    int run = incl - s;
    for (int i = beg, j = 0; i < endi; ++i, ++j) {
        int t = vals[j];
        blockcnt[(size_t)i * nb + b] = run;
        run += t;
    }
    if (lane == 63) bucketTot[b] = incl;
}

// --------------------- P2b: bucket totals -> bucket bases -------------------
__global__ __launch_bounds__(512) void p2b_basescan(
    const int* __restrict__ bucketTot, int* __restrict__ bucketBase, int nb)
{
    __shared__ int tot[NB_MAX];
    int tid = threadIdx.x;
    tot[tid] = (tid < nb) ? bucketTot[tid] : 0;
    __syncthreads();
    for (int off = 1; off < NB_MAX; off <<= 1) {
        int t = (tid >= off) ? tot[tid - off] : 0;
        __syncthreads();
        tot[tid] += t;
        __syncthreads();
    }
    if (tid < nb) bucketBase[tid] = (tid == 0) ? 0 : tot[tid - 1];
    if (tid == 0) bucketBase[nb] = tot[nb - 1];
}

// ---- P4: per-bucket fine CSR, staging runs straight from pairs1 ------------
__global__ __launch_bounds__(256) void p4_fine2(
    const unsigned* __restrict__ pairs1, const int* __restrict__ blockcnt,
    const int* __restrict__ startsTbl, const int* __restrict__ bucketBase,
    int* __restrict__ rowptr, unsigned short* __restrict__ csridx,
    int n, int E, int nb, int chunk, int nblk)
{
    __shared__ unsigned st[STCAP];
    __shared__ int h[BKT_NODES];
    __shared__ int cur[BKT_NODES];
    int tid = threadIdx.x;
    int b = blockIdx.x;
    int beg = bucketBase[b], end = bucketBase[b + 1];
    int cnt = end - beg;
    for (int i = tid; i < BKT_NODES; i += 256) h[i] = 0;
    __syncthreads();
    bool fit = (cnt <= STCAP);     // block-uniform -> in-branch barriers legal
    if (fit) {
        for (int i = tid; i < nblk; i += 256) {
            int ccnt = E - i * chunk; if (ccnt > chunk) ccnt = chunk; if (ccnt < 0) ccnt = 0;
            int stt = startsTbl[(size_t)i * nb + b];
            int enn = (b + 1 < nb) ? startsTbl[(size_t)i * nb + b + 1] : ccnt;
            int dst = blockcnt[(size_t)i * nb + b];
            for (int j = stt; j < enn; ++j)
                st[dst + (j - stt)] = pairs1[(size_t)i * chunk + j];
        }
        __syncthreads();
        for (int i = tid; i < cnt; i += 256)
            atomicAdd(&h[st[i] & (BKT_NODES - 1)], 1);
    } else {
        for (int i = tid; i < nblk; i += 256) {
            int ccnt = E - i * chunk; if (ccnt > chunk) ccnt = chunk; if (ccnt < 0) ccnt = 0;
            int stt = startsTbl[(size_t)i * nb + b];
            int enn = (b + 1 < nb) ? startsTbl[(size_t)i * nb + b + 1] : ccnt;
            for (int j = stt; j < enn; ++j)
                atomicAdd(&h[pairs1[(size_t)i * chunk + j] & (BKT_NODES - 1)], 1);
        }
    }
    // barrier between histogram atomics and scan (round-9 race fix)
    __syncthreads();
    for (int off = 1; off < BKT_NODES; off <<= 1) {
        int t = (tid >= off && tid < BKT_NODES) ? h[tid - off] : 0;
        __syncthreads();
        if (tid < BKT_NODES) h[tid] += t;
        __syncthreads();
    }
    if (tid < BKT_NODES) {
        int node = b * BKT_NODES + tid;
        int startl = (tid == 0) ? 0 : h[tid - 1];
        cur[tid] = startl;
        if (node < n) rowptr[node] = beg + startl;
    }
    __syncthreads();
    if (fit) {
        for (int i = tid; i < cnt; i += 256) {
            unsigned pk = st[i];
            int p = atomicAdd(&cur[pk & (BKT_NODES - 1)], 1);
            csridx[beg + p] = (unsigned short)(pk >> 16);
        }
    } else {
        for (int i = tid; i < nblk; i += 256) {
            int ccnt = E - i * chunk; if (ccnt > chunk) ccnt = chunk; if (ccnt < 0) ccnt = 0;
            int stt = startsTbl[(size_t)i * nb + b];
            int enn = (b + 1 < nb) ? startsTbl[(size_t)i * nb + b + 1] : ccnt;
            for (int j = stt; j < enn; ++j) {
                unsigned pk = pairs1[(size_t)i * chunk + j];
                int p = atomicAdd(&cur[pk & (BKT_NODES - 1)], 1);
                csridx[beg + p] = (unsigned short)(pk >> 16);
            }
        }
    }
    if (b == nb - 1 && tid == 0) rowptr[n] = E;
}

// ------ Fused gather(mean, fp16 table) + dense --------------------------
// r11 structure (fp32 weights in LDS, 35 KB, grid 1024 — occupancy untouched)
// with a PIPELINED gather: 8 lanes x float4 per 128-B row, all 8 batch
// broadcast-indices precomputed, 8 masked loads issued back-to-back so
// 4-8 rows are in flight per wave (was ~1.5: dynamic-bound loop forced
// vmcnt(0) per edge-quad).
template <bool RELU, bool NORM, bool W16>
__global__ __launch_bounds__(256) void fused_sage_kernel(
    const int* __restrict__ rowptr, const unsigned short* __restrict__ csridx,
    const __half* __restrict__ src16, const float* __restrict__ src32,
    const float* __restrict__ W, const float* __restrict__ bvec,
    const float* __restrict__ R, float* __restrict__ out32,
    __half* __restrict__ out16, int n)
{
    __shared__ float Ws[FDIM][FDIM];
    __shared__ float Rs[FDIM][FDIM];
    __shared__ float bs[FDIM];
    __shared__ __align__(16) float aRow[4][FDIM];
    __shared__ float xRow[4][FDIM];
    int tid = threadIdx.x;
    for (int i = tid; i < FDIM * FDIM; i += 256) {
        Ws[i >> 6][i & 63] = W[i];
        Rs[i >> 6][i & 63] = R[i];
    }
    if (tid < FDIM) bs[tid] = bvec[tid];
    __syncthreads();

    int lane = tid & 63, w = tid >> 6;
    int g8 = lane >> 3;       // edge sub-group 0..7
    int q8 = lane & 7;        // 8-feature chunk within row (16 B)

    for (int node = blockIdx.x * 4 + w; node < n; node += gridDim.x * 4) {
        int beg = rowptr[node], end = rowptr[node + 1];
        float4 sLo = make_float4(0.f, 0.f, 0.f, 0.f);   // features 8q8+0..3
        float4 sHi = make_float4(0.f, 0.f, 0.f, 0.f);   // features 8q8+4..7
        for (int base = beg; base < end; base += 64) {
            int cnt = end - base; if (cnt > 64) cnt = 64;
            int ei = base + lane;
            int myidx = (ei < end) ? (int)csridx[ei] : 0;
            int sid[8];
#pragma unroll
            for (int t = 0; t < 8; ++t)
                sid[t] = __shfl(myidx, t * 8 + g8, 64);   // independent bpermutes
#pragma unroll
            for (int t = 0; t < 8; ++t) {
                int e = t * 8 + g8;
                if (e < cnt) {
                    float4 vv = ((const float4*)(src16 + ((size_t)sid[t] << 6)))[q8];
                    const __half2* hp = (const __half2*)&vv;
                    float2 f0 = __half22float2(hp[0]);
                    float2 f1 = __half22float2(hp[1]);
                    float2 f2 = __half22float2(hp[2]);
                    float2 f3 = __half22float2(hp[3]);
                    sLo.x += f0.x; sLo.y += f0.y; sLo.z += f1.x; sLo.w += f1.y;
                    sHi.x += f2.x; sHi.y += f2.y; sHi.z += f3.x; sHi.w += f3.y;
                }
            }
        }
        // combine the 8 edge-groups (lane bits 3..5)
#pragma unroll
        for (int o = 8; o < 64; o <<= 1) {
            sLo.x += __shfl_xor(sLo.x, o, 64);
            sLo.y += __shfl_xor(sLo.y, o, 64);
            sLo.z += __shfl_xor(sLo.z, o, 64);
            sLo.w += __shfl_xor(sLo.w, o, 64);
            sHi.x += __shfl_xor(sHi.x, o, 64);
            sHi.y += __shfl_xor(sHi.y, o, 64);
            sHi.z += __shfl_xor(sHi.z, o, 64);
            sHi.w += __shfl_xor(sHi.w, o, 64);
        }
        float dinv = 1.0f / fmaxf((float)(end - beg), 1.0f);
        if (g8 == 0) {
            *(float4*)&aRow[w][q8 * 8] =
                make_float4(sLo.x * dinv, sLo.y * dinv, sLo.z * dinv, sLo.w * dinv);
            *(float4*)&aRow[w][q8 * 8 + 4] =
                make_float4(sHi.x * dinv, sHi.y * dinv, sHi.z * dinv, sHi.w * dinv);
        }
        xRow[w][lane] = src32[((size_t)node << 6) + lane];
        // wave-local LDS RAW: ordered within the wave, no barrier needed
        float acc = bs[lane];
#pragma unroll
        for (int k = 0; k < FDIM; ++k)
            acc = fmaf(aRow[w][k], Ws[k][lane], fmaf(xRow[w][k], Rs[k][lane], acc));
        if (RELU) acc = fmaxf(acc, 0.0f);
        if (NORM) {
            float ss = acc * acc;
#pragma unroll
            for (int o = 32; o; o >>= 1) ss += __shfl_xor(ss, o, 64);
            acc *= 1.0f / fmaxf(sqrtf(ss), 1e-12f);
        }
        out32[((size_t)node << 6) + lane] = acc;
        if (W16) out16[((size_t)node << 6) + lane] = __float2half(acc);
    }
}

// ----------------- Atomic scatter path (fallback, 13.0 MB ws) ---------------
__global__ __launch_bounds__(256) void scatter_kernel(
    const float* __restrict__ src, const int* __restrict__ rows, const int* __restrict__ cols,
    float* __restrict__ agg, float* __restrict__ deg, int n, long long total)
{
    long long gid = (long long)blockIdx.x * 256 + threadIdx.x;
    if (gid >= total) return;
    int e = (int)(gid >> 6);
    int f = (int)(gid & 63);
    int r = clampi(rows[e], n), c = clampi(cols[e], n);
    atomicAdd(&agg[(long long)c * FDIM + f], src[(long long)r * FDIM + f]);
    if (f == 0) atomicAdd(&deg[c], 1.0f);
}

template <bool RELU, bool NORM>
__global__ __launch_bounds__(256) void dense_kernel(
    const float* __restrict__ agg, const float* __restrict__ deg, const float* __restrict__ x,
    const float* __restrict__ W, const float* __restrict__ b,
    const float* __restrict__ R, float* __restrict__ out, int n)
{
    __shared__ float Ws[FDIM][FDIM];
    __shared__ float Rs[FDIM][FDIM];
    __shared__ float bs[FDIM];
    __shared__ float aRow[4][FDIM];
    __shared__ float xRow[4][FDIM];
    int tid = threadIdx.x;
    for (int i = tid; i < FDIM * FDIM; i += 256) {
        Ws[i >> 6][i & 63] = W[i];
        Rs[i >> 6][i & 63] = R[i];
    }
    if (tid < FDIM) bs[tid] = b[tid];
    int j = tid & 63, r = tid >> 6;
    int row = blockIdx.x * 4 + r;
    if (row < n) {
        float d = fmaxf(deg[row], 1.0f);
        aRow[r][j] = agg[(long long)row * FDIM + j] / d;
        xRow[r][j] = x[(long long)row * FDIM + j];
    }
    __syncthreads();
    if (row >= n) return;
    float acc = bs[j];
#pragma unroll
    for (int k = 0; k < FDIM; ++k)
        acc = fmaf(aRow[r][k], Ws[k][j], fmaf(xRow[r][k], Rs[k][j], acc));
    if (RELU) acc = fmaxf(acc, 0.0f);
    if (NORM) {
        float ss = acc * acc;
#pragma unroll
        for (int o = 32; o; o >>= 1) ss += __shfl_xor(ss, o, 64);
        acc *= 1.0f / fmaxf(sqrtf(ss), 1e-12f);
    }
    out[(long long)row * FDIM + j] = acc;
}

// ---------------------------------------------------------------------------
extern "C" void kernel_launch(void* const* d_in, const int* in_sizes, int n_in,
                              void* d_out, int out_size, void* d_ws, size_t ws_size,
                              hipStream_t stream)
{
    const float* x  = (const float*)d_in[0];
    const int*   e0 = (const int*)d_in[1];
    const int*   e1 = (const int*)d_in[2];
    const float* W1 = (const float*)d_in[3];
    const float* b1 = (const float*)d_in[4];
    const float* R1 = (const float*)d_in[5];
    const float* W2 = (const float*)d_in[6];
    const float* b2 = (const float*)d_in[7];
    const float* R2 = (const float*)d_in[8];
    float* out = (float*)d_out;

    const int N = in_sizes[0] / FDIM;     // 50000
    const int E = in_sizes[1] / 2;        // 1600000

    const int nb = (N + BKT_NODES - 1) >> BKT_SHIFT;
    const int chunk = (E + NBLK_G - 1) / NBLK_G;
    const int FUSED_BLOCKS = 1024;        // r7-proven: 4 blocks/CU at 35 KB LDS

    // Workspace (16-B aligned): pairs1[E] u32 | csridx[E] u16 |
    // blockcnt[NBLK_G*nb] | startsTbl[NBLK_G*nb] | bucketBase[nb+1] |
    // bucketTot[nb] | rowptr[N+1] | x16[N*64] half | h16[N*64] half  (~24.4 MB)
    auto align16 = [](size_t v) { return (v + 15) & ~(size_t)15; };
    size_t off = 0;
    size_t o_pairs1 = off; off = align16(off + (size_t)E * 4);
    size_t o_csr16  = off; off = align16(off + (size_t)E * 2);
    size_t o_bcnt   = off; off = align16(off + (size_t)NBLK_G * nb * 4);
    size_t o_stbl   = off; off = align16(off + (size_t)NBLK_G * nb * 4);
    size_t o_bbase  = off; off = align16(off + (size_t)(nb + 1) * 4);
    size_t o_btot   = off; off = align16(off + (size_t)nb * 4);
    size_t o_rowp   = off; off = align16(off + (size_t)(N + 1) * 4);
    size_t o_x16    = off; off = align16(off + (size_t)N * FDIM * 2);
    size_t o_h16    = off; off = align16(off + (size_t)N * FDIM * 2);
    const size_t need1 = off;

    const bool ok1 = (ws_size >= need1) && (N <= 65536) &&
                     (chunk <= CHUNK_CAP) && (nb <= NB_MAX) &&
                     ((N * FDIM & 3) == 0);

    if (ok1) {
        char* wsb = (char*)d_ws;
        unsigned*        pairs1     = (unsigned*)(wsb + o_pairs1);
        unsigned short*  csridx     = (unsigned short*)(wsb + o_csr16);
        int*             blockcnt   = (int*)(wsb + o_bcnt);
        int*             startsTbl  = (int*)(wsb + o_stbl);
        int*             bucketBase = (int*)(wsb + o_bbase);
        int*             bucketTot  = (int*)(wsb + o_btot);
        int*             rowptr     = (int*)(wsb + o_rowp);
        __half*          x16        = (__half*)(wsb + o_x16);
        __half*          h16        = (__half*)(wsb + o_h16);
        float*           h32        = out;   // layer-1 hidden lives in d_out

        const int n4 = N * FDIM / 4;
        convert_half4<<<(n4 + 255) / 256, 256, 0, stream>>>(
            (const float4*)x, (__half2*)x16, n4);

        // ---- Layer 1 ----
        p1_bin_stage<<<NBLK_G, 512, 0, stream>>>(e0, e0 + E, pairs1, blockcnt,
                                                 startsTbl, N, E, nb, chunk);
        p2a_colscan<<<nb, 64, 0, stream>>>(blockcnt, bucketTot, nb, NBLK_G);
        p2b_basescan<<<1, 512, 0, stream>>>(bucketTot, bucketBase, nb);
        p4_fine2<<<nb, 256, 0, stream>>>(pairs1, blockcnt, startsTbl, bucketBase,
                                         rowptr, csridx, N, E, nb, chunk, NBLK_G);
        fused_sage_kernel<true, false, true><<<FUSED_BLOCKS, 256, 0, stream>>>(
            rowptr, csridx, x16, x, W1, b1, R1, h32, h16, N);

        // ---- Layer 2 ----
        p1_bin_stage<<<NBLK_G, 512, 0, stream>>>(e1, e1 + E, pairs1, blockcnt,
                                                 startsTbl, N, E, nb, chunk);
        p2a_colscan<<<nb, 64, 0, stream>>>(blockcnt, bucketTot, nb, NBLK_G);
        p2b_basescan<<<1, 512, 0, stream>>>(bucketTot, bucketBase, nb);
        p4_fine2<<<nb, 256, 0, stream>>>(pairs1, blockcnt, startsTbl, bucketBase,
                                         rowptr, csridx, N, E, nb, chunk, NBLK_G);
        // in-place over d_out: gather reads h16, each thread reads only its
        // own h32 row before overwriting it
        fused_sage_kernel<false, true, false><<<FUSED_BLOCKS, 256, 0, stream>>>(
            rowptr, csridx, h16, h32, W2, b2, R2, out, (__half*)nullptr, N);
    } else {
        // Fallback: atomic scatter path (round-3, verified)
        float* agg = (float*)d_ws;
        float* deg = agg + (long long)N * FDIM;
        float* h = out;
        const long long total = (long long)E * FDIM;
        const int sblocks = (int)((total + 255) / 256);
        const int dblocks = (N + 3) / 4;

        hipMemsetAsync(agg, 0, ((size_t)N * FDIM + N) * sizeof(float), stream);
        scatter_kernel<<<sblocks, 256, 0, stream>>>(x, e0, e0 + E, agg, deg, N, total);
        dense_kernel<true, false><<<dblocks, 256, 0, stream>>>(agg, deg, x, W1, b1, R1, h, N);

        hipMemsetAsync(agg, 0, ((size_t)N * FDIM + N) * sizeof(float), stream);
        scatter_kernel<<<sblocks, 256, 0, stream>>>(h, e1, e1 + E, agg, deg, N, total);
        dense_kernel<false, true><<<dblocks, 256, 0, stream>>>(agg, deg, h, W2, b2, R2, out, N);
    }
}

// Round 13
// 307.741 us; speedup vs baseline: 1.2236x; 1.2236x over previous
//
#include <hip/hip_runtime.h>
#include <hip/hip_bf16.h>
#include <hip/hip_fp16.h>

#define FDIM 64
#define WPAD 68   // transposed-weight row stride (floats): 272 B, 16 B-aligned,
                  // bank=(4*lane+4k+i)%32 -> optimal 8 accesses/bank for b128

// Bucketed CSR build parameters
#define NBLK_G 256        // chunk-grid for p1
#define CHUNK_CAP 8192    // max edges per chunk block (32 KB LDS stage)
#define BKT_SHIFT 7
#define BKT_NODES 128     // dest nodes per bucket
#define NB_MAX 512        // max buckets (N <= 65536)
#define STCAP 8192        // P4 LDS stage cap (edges)

__device__ __forceinline__ int clampi(int v, int n) { return min(max(v, 0), n - 1); }

// --------------------- convert fp32 -> fp16 shadow table (x4) ---------------
__global__ __launch_bounds__(256) void convert_half4(
    const float4* __restrict__ in4, __half2* __restrict__ out2, int n4)
{
    int i = blockIdx.x * 256 + threadIdx.x;
    if (i >= n4) return;
    float4 v = in4[i];
    out2[2 * i]     = __floats2half2_rn(v.x, v.y);
    out2[2 * i + 1] = __floats2half2_rn(v.z, v.w);
}

// ---- P1: block-local bin + contiguous stage + counts + starts table --------
__global__ __launch_bounds__(512) void p1_bin_stage(
    const int* __restrict__ rows, const int* __restrict__ cols,
    unsigned* __restrict__ pairs1, int* __restrict__ blockcnt,
    int* __restrict__ startsTbl, int n, int E, int nb, int chunk)
{
    __shared__ unsigned stage[CHUNK_CAP];
    __shared__ int hist[NB_MAX];
    __shared__ int curs[NB_MAX];
    int tid = threadIdx.x;
    int base = blockIdx.x * chunk;
    int cnt = E - base; if (cnt > chunk) cnt = chunk; if (cnt < 0) cnt = 0;
    for (int i = tid; i < NB_MAX; i += 512) hist[i] = 0;
    __syncthreads();
    for (int i = tid; i < cnt; i += 512)
        atomicAdd(&hist[clampi(cols[base + i], n) >> BKT_SHIFT], 1);
    __syncthreads();
    for (int b = tid; b < nb; b += 512) blockcnt[blockIdx.x * nb + b] = hist[b];
    __syncthreads();
    for (int off = 1; off < NB_MAX; off <<= 1) {
        int t = (tid >= off) ? hist[tid - off] : 0;
        __syncthreads();
        hist[tid] += t;
        __syncthreads();
    }
    curs[tid] = (tid == 0) ? 0 : hist[tid - 1];
    __syncthreads();
    // persist chunk-local exclusive starts BEFORE atomics mutate curs
    for (int b = tid; b < nb; b += 512) startsTbl[blockIdx.x * nb + b] = curs[b];
    __syncthreads();
    for (int i = tid; i < cnt; i += 512) {
        int c = clampi(cols[base + i], n);
        int r = clampi(rows[base + i], n);
        int p = atomicAdd(&curs[c >> BKT_SHIFT], 1);
        stage[p] = ((unsigned)r << 16) | (unsigned)c;
    }
    __syncthreads();
    for (int i = tid; i < cnt; i += 512) pairs1[base + i] = stage[i];
}

// --------------------- P2a: per-bucket column scan (1 wave / bucket) --------
__global__ __launch_bounds__(64) void p2a_colscan(
    int* __restrict__ blockcnt, int* __restrict__ bucketTot, int nb, int nblk)
{
    int b = blockIdx.x;
    int lane = threadIdx.x;
    int chunk = (nblk + 63) >> 6;
    int beg = lane * chunk;
    int endi = min(beg + chunk, nblk);
    int vals[8];
    int s = 0;
    for (int i = beg, j = 0; i < endi; ++i, ++j) {
        vals[j] = blockcnt[(size_t)i * nb + b];
        s += vals[j];
    }
    int incl = s;
#pragma unroll
    for (int o = 1; o < 64; o <<= 1) {
        int t = __shfl_up(incl, o, 64);
        if (lane >= o) incl += t;
    }
    int run = incl - s;
    for (int i = beg, j = 0; i < endi; ++i, ++j) {
        int t = vals[j];
        blockcnt[(size_t)i * nb + b] = run;
        run += t;
    }
    if (lane == 63) bucketTot[b] = incl;
}

// --------------------- P2b: bucket totals -> bucket bases -------------------
__global__ __launch_bounds__(512) void p2b_basescan(
    const int* __restrict__ bucketTot, int* __restrict__ bucketBase, int nb)
{
    __shared__ int tot[NB_MAX];
    int tid = threadIdx.x;
    tot[tid] = (tid < nb) ? bucketTot[tid] : 0;
    __syncthreads();
    for (int off = 1; off < NB_MAX; off <<= 1) {
        int t = (tid >= off) ? tot[tid - off] : 0;
        __syncthreads();
        tot[tid] += t;
        __syncthreads();
    }
    if (tid < nb) bucketBase[tid] = (tid == 0) ? 0 : tot[tid - 1];
    if (tid == 0) bucketBase[nb] = tot[nb - 1];
}

// ---- P4: per-bucket fine CSR, staging runs straight from pairs1 ------------
__global__ __launch_bounds__(256) void p4_fine2(
    const unsigned* __restrict__ pairs1, const int* __restrict__ blockcnt,
    const int* __restrict__ startsTbl, const int* __restrict__ bucketBase,
    int* __restrict__ rowptr, unsigned short* __restrict__ csridx,
    int n, int E, int nb, int chunk, int nblk)
{
    __shared__ unsigned st[STCAP];
    __shared__ int h[BKT_NODES];
    __shared__ int cur[BKT_NODES];
    int tid = threadIdx.x;
    int b = blockIdx.x;
    int beg = bucketBase[b], end = bucketBase[b + 1];
    int cnt = end - beg;
    for (int i = tid; i < BKT_NODES; i += 256) h[i] = 0;
    __syncthreads();
    bool fit = (cnt <= STCAP);     // block-uniform -> in-branch barriers legal
    if (fit) {
        for (int i = tid; i < nblk; i += 256) {
            int ccnt = E - i * chunk; if (ccnt > chunk) ccnt = chunk; if (ccnt < 0) ccnt = 0;
            int stt = startsTbl[(size_t)i * nb + b];
            int enn = (b + 1 < nb) ? startsTbl[(size_t)i * nb + b + 1] : ccnt;
            int dst = blockcnt[(size_t)i * nb + b];
            for (int j = stt; j < enn; ++j)
                st[dst + (j - stt)] = pairs1[(size_t)i * chunk + j];
        }
        __syncthreads();
        for (int i = tid; i < cnt; i += 256)
            atomicAdd(&h[st[i] & (BKT_NODES - 1)], 1);
    } else {
        for (int i = tid; i < nblk; i += 256) {
            int ccnt = E - i * chunk; if (ccnt > chunk) ccnt = chunk; if (ccnt < 0) ccnt = 0;
            int stt = startsTbl[(size_t)i * nb + b];
            int enn = (b + 1 < nb) ? startsTbl[(size_t)i * nb + b + 1] : ccnt;
            for (int j = stt; j < enn; ++j)
                atomicAdd(&h[pairs1[(size_t)i * chunk + j] & (BKT_NODES - 1)], 1);
        }
    }
    // barrier between histogram atomics and scan (round-9 race fix)
    __syncthreads();
    for (int off = 1; off < BKT_NODES; off <<= 1) {
        int t = (tid >= off && tid < BKT_NODES) ? h[tid - off] : 0;
        __syncthreads();
        if (tid < BKT_NODES) h[tid] += t;
        __syncthreads();
    }
    if (tid < BKT_NODES) {
        int node = b * BKT_NODES + tid;
        int startl = (tid == 0) ? 0 : h[tid - 1];
        cur[tid] = startl;
        if (node < n) rowptr[node] = beg + startl;
    }
    __syncthreads();
    if (fit) {
        for (int i = tid; i < cnt; i += 256) {
            unsigned pk = st[i];
            int p = atomicAdd(&cur[pk & (BKT_NODES - 1)], 1);
            csridx[beg + p] = (unsigned short)(pk >> 16);
        }
    } else {
        for (int i = tid; i < nblk; i += 256) {
            int ccnt = E - i * chunk; if (ccnt > chunk) ccnt = chunk; if (ccnt < 0) ccnt = 0;
            int stt = startsTbl[(size_t)i * nb + b];
            int enn = (b + 1 < nb) ? startsTbl[(size_t)i * nb + b + 1] : ccnt;
            for (int j = stt; j < enn; ++j) {
                unsigned pk = pairs1[(size_t)i * chunk + j];
                int p = atomicAdd(&cur[pk & (BKT_NODES - 1)], 1);
                csridx[beg + p] = (unsigned short)(pk >> 16);
            }
        }
    }
    if (b == nb - 1 && tid == 0) rowptr[n] = E;
}

// ------ Fused gather(mean, fp16 table) + dense ------------------------------
// r7/r11 gather VERBATIM (the only config holding 39% occupancy; VGPR must
// stay <=~64). Epilogue only change: W,R stored TRANSPOSED+padded in LDS so
// the k-loop is 16x {4x ds_read_b128 + 16 FMA} = 64 LDS instr/node (was 256
// ds_read_b32 — the measured 83us = LDS-pipe arithmetic closes exactly).
template <bool RELU, bool NORM, bool W16>
__global__ __launch_bounds__(256) void fused_sage_kernel(
    const int* __restrict__ rowptr, const unsigned short* __restrict__ csridx,
    const __half* __restrict__ src16, const float* __restrict__ src32,
    const float* __restrict__ W, const float* __restrict__ bvec,
    const float* __restrict__ R, float* __restrict__ out32,
    __half* __restrict__ out16, int n)
{
    __shared__ __align__(16) float Wt[FDIM][WPAD];   // Wt[j][k] = W[k][j]
    __shared__ __align__(16) float Rt[FDIM][WPAD];
    __shared__ float bs[FDIM];
    __shared__ __align__(16) float aRow[4][FDIM];
    __shared__ __align__(16) float xRow[4][FDIM];
    int tid = threadIdx.x;
    for (int i = tid; i < FDIM * FDIM; i += 256) {
        int k = i >> 6, j = i & 63;
        Wt[j][k] = W[i];           // W row-major [k][j]
        Rt[j][k] = R[i];
    }
    if (tid < FDIM) bs[tid] = bvec[tid];
    __syncthreads();

    int lane = tid & 63, w = tid >> 6;
    int g = lane >> 4;        // edge sub-group 0..3
    int q = lane & 15;        // 4-feature chunk within row

    for (int node = blockIdx.x * 4 + w; node < n; node += gridDim.x * 4) {
        int beg = rowptr[node], end = rowptr[node + 1];
        float4 s4 = make_float4(0.f, 0.f, 0.f, 0.f);
        for (int base = beg; base < end; base += 64) {
            int cnt = end - base; if (cnt > 64) cnt = 64;
            int ei = base + lane;
            int myidx = (ei < end) ? (int)csridx[ei] : 0;
            int steps = (cnt + 3) >> 2;
            for (int t = 0; t < steps; ++t) {
                int e = (t << 2) | g;
                int sidx = __shfl(myidx, e, 64);
                if (e < cnt) {
                    const float2* rp = (const float2*)(src16 + ((size_t)sidx << 6));
                    float2 vv = rp[q];                 // 4 halves = 8 B
                    __half2 ha = *reinterpret_cast<__half2*>(&vv.x);
                    __half2 hb = *reinterpret_cast<__half2*>(&vv.y);
                    float2 fa = __half22float2(ha);
                    float2 fb = __half22float2(hb);
                    s4.x += fa.x; s4.y += fa.y; s4.z += fb.x; s4.w += fb.y;
                }
            }
        }
#pragma unroll
        for (int o = 16; o < 64; o <<= 1) {
            s4.x += __shfl_xor(s4.x, o, 64);
            s4.y += __shfl_xor(s4.y, o, 64);
            s4.z += __shfl_xor(s4.z, o, 64);
            s4.w += __shfl_xor(s4.w, o, 64);
        }
        float dinv = 1.0f / fmaxf((float)(end - beg), 1.0f);
        if (g == 0) {
            aRow[w][q * 4 + 0] = s4.x * dinv;
            aRow[w][q * 4 + 1] = s4.y * dinv;
            aRow[w][q * 4 + 2] = s4.z * dinv;
            aRow[w][q * 4 + 3] = s4.w * dinv;
        }
        xRow[w][lane] = src32[((size_t)node << 6) + lane];
        // wave-local LDS RAW: ordered within the wave, no barrier needed
        float acc = bs[lane];
#pragma unroll
        for (int k4 = 0; k4 < FDIM / 4; ++k4) {
            float4 a4 = *(const float4*)&aRow[w][k4 * 4];   // broadcast b128
            float4 x4 = *(const float4*)&xRow[w][k4 * 4];
            float4 w4 = *(const float4*)&Wt[lane][k4 * 4];  // b128, 8/bank
            float4 r4 = *(const float4*)&Rt[lane][k4 * 4];
            acc = fmaf(a4.x, w4.x, acc);
            acc = fmaf(a4.y, w4.y, acc);
            acc = fmaf(a4.z, w4.z, acc);
            acc = fmaf(a4.w, w4.w, acc);
            acc = fmaf(x4.x, r4.x, acc);
            acc = fmaf(x4.y, r4.y, acc);
            acc = fmaf(x4.z, r4.z, acc);
            acc = fmaf(x4.w, r4.w, acc);
        }
        if (RELU) acc = fmaxf(acc, 0.0f);
        if (NORM) {
            float ss = acc * acc;
#pragma unroll
            for (int o = 32; o; o >>= 1) ss += __shfl_xor(ss, o, 64);
            acc *= 1.0f / fmaxf(sqrtf(ss), 1e-12f);
        }
        out32[((size_t)node << 6) + lane] = acc;
        if (W16) out16[((size_t)node << 6) + lane] = __float2half(acc);
    }
}

// ----------------- Atomic scatter path (fallback, 13.0 MB ws) ---------------
__global__ __launch_bounds__(256) void scatter_kernel(
    const float* __restrict__ src, const int* __restrict__ rows, const int* __restrict__ cols,
    float* __restrict__ agg, float* __restrict__ deg, int n, long long total)
{
    long long gid = (long long)blockIdx.x * 256 + threadIdx.x;
    if (gid >= total) return;
    int e = (int)(gid >> 6);
    int f = (int)(gid & 63);
    int r = clampi(rows[e], n), c = clampi(cols[e], n);
    atomicAdd(&agg[(long long)c * FDIM + f], src[(long long)r * FDIM + f]);
    if (f == 0) atomicAdd(&deg[c], 1.0f);
}

template <bool RELU, bool NORM>
__global__ __launch_bounds__(256) void dense_kernel(
    const float* __restrict__ agg, const float* __restrict__ deg, const float* __restrict__ x,
    const float* __restrict__ W, const float* __restrict__ b,
    const float* __restrict__ R, float* __restrict__ out, int n)
{
    __shared__ float Ws[FDIM][FDIM];
    __shared__ float Rs[FDIM][FDIM];
    __shared__ float bs[FDIM];
    __shared__ float aRow[4][FDIM];
    __shared__ float xRow[4][FDIM];
    int tid = threadIdx.x;
    for (int i = tid; i < FDIM * FDIM; i += 256) {
        Ws[i >> 6][i & 63] = W[i];
        Rs[i >> 6][i & 63] = R[i];
    }
    if (tid < FDIM) bs[tid] = b[tid];
    int j = tid & 63, r = tid >> 6;
    int row = blockIdx.x * 4 + r;
    if (row < n) {
        float d = fmaxf(deg[row], 1.0f);
        aRow[r][j] = agg[(long long)row * FDIM + j] / d;
        xRow[r][j] = x[(long long)row * FDIM + j];
    }
    __syncthreads();
    if (row >= n) return;
    float acc = bs[j];
#pragma unroll
    for (int k = 0; k < FDIM; ++k)
        acc = fmaf(aRow[r][k], Ws[k][j], fmaf(xRow[r][k], Rs[k][j], acc));
    if (RELU) acc = fmaxf(acc, 0.0f);
    if (NORM) {
        float ss = acc * acc;
#pragma unroll
        for (int o = 32; o; o >>= 1) ss += __shfl_xor(ss, o, 64);
        acc *= 1.0f / fmaxf(sqrtf(ss), 1e-12f);
    }
    out[(long long)row * FDIM + j] = acc;
}

// ---------------------------------------------------------------------------
extern "C" void kernel_launch(void* const* d_in, const int* in_sizes, int n_in,
                              void* d_out, int out_size, void* d_ws, size_t ws_size,
                              hipStream_t stream)
{
    const float* x  = (const float*)d_in[0];
    const int*   e0 = (const int*)d_in[1];
    const int*   e1 = (const int*)d_in[2];
    const float* W1 = (const float*)d_in[3];
    const float* b1 = (const float*)d_in[4];
    const float* R1 = (const float*)d_in[5];
    const float* W2 = (const float*)d_in[6];
    const float* b2 = (const float*)d_in[7];
    const float* R2 = (const float*)d_in[8];
    float* out = (float*)d_out;

    const int N = in_sizes[0] / FDIM;     // 50000
    const int E = in_sizes[1] / 2;        // 1600000

    const int nb = (N + BKT_NODES - 1) >> BKT_SHIFT;
    const int chunk = (E + NBLK_G - 1) / NBLK_G;
    const int FUSED_BLOCKS = 1024;        // 4 blocks/CU at ~37 KB LDS

    // Workspace (16-B aligned): pairs1[E] u32 | csridx[E] u16 |
    // blockcnt[NBLK_G*nb] | startsTbl[NBLK_G*nb] | bucketBase[nb+1] |
    // bucketTot[nb] | rowptr[N+1] | x16[N*64] half | h16[N*64] half  (~24.4 MB)
    auto align16 = [](size_t v) { return (v + 15) & ~(size_t)15; };
    size_t off = 0;
    size_t o_pairs1 = off; off = align16(off + (size_t)E * 4);
    size_t o_csr16  = off; off = align16(off + (size_t)E * 2);
    size_t o_bcnt   = off; off = align16(off + (size_t)NBLK_G * nb * 4);
    size_t o_stbl   = off; off = align16(off + (size_t)NBLK_G * nb * 4);
    size_t o_bbase  = off; off = align16(off + (size_t)(nb + 1) * 4);
    size_t o_btot   = off; off = align16(off + (size_t)nb * 4);
    size_t o_rowp   = off; off = align16(off + (size_t)(N + 1) * 4);
    size_t o_x16    = off; off = align16(off + (size_t)N * FDIM * 2);
    size_t o_h16    = off; off = align16(off + (size_t)N * FDIM * 2);
    const size_t need1 = off;

    const bool ok1 = (ws_size >= need1) && (N <= 65536) &&
                     (chunk <= CHUNK_CAP) && (nb <= NB_MAX) &&
                     ((N * FDIM & 3) == 0);

    if (ok1) {
        char* wsb = (char*)d_ws;
        unsigned*        pairs1     = (unsigned*)(wsb + o_pairs1);
        unsigned short*  csridx     = (unsigned short*)(wsb + o_csr16);
        int*             blockcnt   = (int*)(wsb + o_bcnt);
        int*             startsTbl  = (int*)(wsb + o_stbl);
        int*             bucketBase = (int*)(wsb + o_bbase);
        int*             bucketTot  = (int*)(wsb + o_btot);
        int*             rowptr     = (int*)(wsb + o_rowp);
        __half*          x16        = (__half*)(wsb + o_x16);
        __half*          h16        = (__half*)(wsb + o_h16);
        float*           h32        = out;   // layer-1 hidden lives in d_out

        const int n4 = N * FDIM / 4;
        convert_half4<<<(n4 + 255) / 256, 256, 0, stream>>>(
            (const float4*)x, (__half2*)x16, n4);

        // ---- Layer 1 ----
        p1_bin_stage<<<NBLK_G, 512, 0, stream>>>(e0, e0 + E, pairs1, blockcnt,
                                                 startsTbl, N, E, nb, chunk);
        p2a_colscan<<<nb, 64, 0, stream>>>(blockcnt, bucketTot, nb, NBLK_G);
        p2b_basescan<<<1, 512, 0, stream>>>(bucketTot, bucketBase, nb);
        p4_fine2<<<nb, 256, 0, stream>>>(pairs1, blockcnt, startsTbl, bucketBase,
                                         rowptr, csridx, N, E, nb, chunk, NBLK_G);
        fused_sage_kernel<true, false, true><<<FUSED_BLOCKS, 256, 0, stream>>>(
            rowptr, csridx, x16, x, W1, b1, R1, h32, h16, N);

        // ---- Layer 2 ----
        p1_bin_stage<<<NBLK_G, 512, 0, stream>>>(e1, e1 + E, pairs1, blockcnt,
                                                 startsTbl, N, E, nb, chunk);
        p2a_colscan<<<nb, 64, 0, stream>>>(blockcnt, bucketTot, nb, NBLK_G);
        p2b_basescan<<<1, 512, 0, stream>>>(bucketTot, bucketBase, nb);
        p4_fine2<<<nb, 256, 0, stream>>>(pairs1, blockcnt, startsTbl, bucketBase,
                                         rowptr, csridx, N, E, nb, chunk, NBLK_G);
        // in-place over d_out: gather reads h16, each thread reads only its
        // own h32 row before overwriting it
        fused_sage_kernel<false, true, false><<<FUSED_BLOCKS, 256, 0, stream>>>(
            rowptr, csridx, h16, h32, W2, b2, R2, out, (__half*)nullptr, N);
    } else {
        // Fallback: atomic scatter path (round-3, verified)
        float* agg = (float*)d_ws;
        float* deg = agg + (long long)N * FDIM;
        float* h = out;
        const long long total = (long long)E * FDIM;
        const int sblocks = (int)((total + 255) / 256);
        const int dblocks = (N + 3) / 4;

        hipMemsetAsync(agg, 0, ((size_t)N * FDIM + N) * sizeof(float), stream);
        scatter_kernel<<<sblocks, 256, 0, stream>>>(x, e0, e0 + E, agg, deg, N, total);
        dense_kernel<true, false><<<dblocks, 256, 0, stream>>>(agg, deg, x, W1, b1, R1, h, N);

        hipMemsetAsync(agg, 0, ((size_t)N * FDIM + N) * sizeof(float), stream);
        scatter_kernel<<<sblocks, 256, 0, stream>>>(h, e1, e1 + E, agg, deg, N, total);
        dense_kernel<false, true><<<dblocks, 256, 0, stream>>>(agg, deg, h, W2, b2, R2, out, N);
    }
}